// Round 7
// baseline (47418.341 us; speedup 1.0000x reference)
//
#include <hip/hip_runtime.h>
#include <math.h>

#define L_SEQ 8192
#define I_DIM 256
#define H_DIM 2048
#define NWG0  64          // layer-0: 64 WGs x 32 rows (4 rows/wave, col-block per lane)
#define NWG1  128         // layer-1: 128 WGs x 16 rows (2 rows/wave)
#define NWG   (NWG0 + NWG1)
#define TPB   512

// ws: [0] runctr | [256..1024) bslots | [4096) h0 ring 8*2048 f32 | [+64K) h1 ring
//
// Protocol = round-4's tagged dataflow (proven): value = h + ctr(step),
// ctr = 4+8*((step>>3)&1), ring depth 8, valid iff |v-ctr|<=1; slots re-inited
// per run (slot0 = tagged h_0, slots 1-7 = 0.0f invalid); poison/0.0 never match;
// start barrier on monotone runctr. Throttle: every 4th step s, L0 verifies all
// L1 WGs published h1_{s-4} (sentinel row per WG). Safety: overwriting slot s&7
// (data s-8) needs consumers past s-8: L0 peers >= s-1 (validated h0_{s-1});
// L1 >= s'-4 >= s-7 reading h0_{>= s-6} > s-8. Tag aliasing needs spread >= 16;
// max spread <= 7. FC: throttle at s=8192 gives L1 >= 8188 => h1 slot 0 holds
// step 8184 (ctr 12, invalid) or 8192 (ctr 4) -- never the 4.0 init.
//
// Compute = column-block form (NEW): lane l owns cols [32l,32l+32) for its
// wave's rows; reads ONLY its 8 float4 of h per matrix from LDS (pad-swizzled
// pos = j + (j>>3): conflict-free); row sum via 6-level shfl_xor; lane 0
// publishes. LDS traffic/WG/step: L0 72 KB, L1 128 KB (was 288/256 KB).
// Weights = NAMED float4 scalars via macros (no arrays -> no SROA-to-scratch),
// loaded by asm-opaque ld4 (no remat). L0 36 f4, L1 32 f4 per thread.

__device__ __forceinline__ void cstore1(float* p, float v) {
  asm volatile("global_store_dword %0, %1, off sc0 sc1" :: "v"(p), "v"(v) : "memory");
}
__device__ __forceinline__ void cstoreu(unsigned* p, unsigned v) {
  asm volatile("global_store_dword %0, %1, off sc0 sc1" :: "v"(p), "v"(v) : "memory");
}
__device__ __forceinline__ float cload1(const float* p) {
  float v;
  asm volatile("global_load_dword %0, %1, off sc0 sc1\n\ts_waitcnt vmcnt(0)"
               : "=v"(v) : "v"(p) : "memory");
  return v;
}
__device__ __forceinline__ unsigned cloadu(const unsigned* p) {
  unsigned v;
  asm volatile("global_load_dword %0, %1, off sc0 sc1\n\ts_waitcnt vmcnt(0)"
               : "=v"(v) : "v"(p) : "memory");
  return v;
}
__device__ __forceinline__ float4 cload4(const float* p) {
  float4 v;
  asm volatile("global_load_dwordx4 %0, %1, off sc0 sc1\n\ts_waitcnt vmcnt(0)"
               : "=v"(v) : "v"(p) : "memory");
  return v;
}
__device__ __forceinline__ void cload4x2(const float* p0, const float* p1, float4& a, float4& b) {
  asm volatile("global_load_dwordx4 %0, %2, off sc0 sc1\n\t"
               "global_load_dwordx4 %1, %3, off sc0 sc1\n\t"
               "s_waitcnt vmcnt(0)"
               : "=&v"(a), "=&v"(b) : "v"(p0), "v"(p1) : "memory");
}
__device__ __forceinline__ float4 ld4(const float* p) {   // weight load, opaque
  float4 v;
  asm volatile("global_load_dwordx4 %0, %1, off\n\ts_waitcnt vmcnt(0)"
               : "=v"(v) : "v"(p) : "memory");
  return v;
}
__device__ __forceinline__ float tagc(int step) {
  return 4.f + 8.f * (float)((step >> 3) & 1);
}
__device__ __forceinline__ bool ok4(float4 v, float c) {
  return __builtin_fabsf(v.x - c) <= 1.f && __builtin_fabsf(v.y - c) <= 1.f &&
         __builtin_fabsf(v.z - c) <= 1.f && __builtin_fabsf(v.w - c) <= 1.f;
}
__device__ __forceinline__ float4 poll4(const float* p, float c) {
  for (;;) {
    float4 v = cload4(p);
    if (ok4(v, c)) return make_float4(v.x - c, v.y - c, v.z - c, v.w - c);
  }
}
__device__ __forceinline__ void poll4x2(const float* p0, float c0,
                                        const float* p1, float c1,
                                        float4& a, float4& b) {
  for (;;) {
    float4 u, v;
    cload4x2(p0, p1, u, v);
    if (ok4(u, c0) && ok4(v, c1)) {
      a = make_float4(u.x - c0, u.y - c0, u.z - c0, u.w - c0);
      b = make_float4(v.x - c1, v.y - c1, v.z - c1, v.w - c1);
      return;
    }
  }
}
__device__ __forceinline__ float tanh_fast(float v) {   // exact identity, ~1 ulp
  float e = __expf(2.f * v);
  return 1.f - 2.f / (e + 1.f);
}
__device__ __forceinline__ void start_barrier(unsigned* bslots, int wg, int tid, unsigned value) {
  __syncthreads();
  if (tid == 0) cstoreu(&bslots[wg], value);
  if (tid < NWG) {
    while ((int)(cloadu(&bslots[tid]) - value) < 0) __builtin_amdgcn_s_sleep(1);
  }
  __syncthreads();
}

#define K8(M) M(0) M(1) M(2) M(3) M(4) M(5) M(6) M(7)
#define MAC4(A, W, H) \
  A.x = __builtin_fmaf((W).x, (H).x, A.x); A.y = __builtin_fmaf((W).y, (H).y, A.y); \
  A.z = __builtin_fmaf((W).z, (H).z, A.z); A.w = __builtin_fmaf((W).w, (H).w, A.w);

__global__ __launch_bounds__(TPB, 2)
void rnn2_colblock(const float* __restrict__ x,
                   const float* __restrict__ Wih0, const float* __restrict__ Whh0,
                   const float* __restrict__ bih0, const float* __restrict__ bhh0,
                   const float* __restrict__ Wih1, const float* __restrict__ Whh1,
                   const float* __restrict__ bih1, const float* __restrict__ bhh1,
                   const float* __restrict__ Wfc,  const float* __restrict__ bfc,
                   float* __restrict__ out,
                   unsigned* __restrict__ runctr, unsigned* __restrict__ bslots,
                   float* __restrict__ h0s, float* __restrict__ h1s)
{
  const int wg   = blockIdx.x;
  const int tid  = threadIdx.x;
  const int lane = tid & 63;
  const int wv   = tid >> 6;

  __shared__ float4 h0l[2][576];
  __shared__ float4 h1l[2][576];
  __shared__ float4 xl[2][72];

  const unsigned runbase = cloadu(runctr);

  if (wg < NWG0) {
    // ========== layer 0: rows r0..r0+3 = wg*32 + wv*4 .. ; cols [32*lane,+32) ==========
    const int r0 = wg * 32 + wv * 4;
    #define DCL0(k) float4 wa0_##k, wa1_##k, wa2_##k, wa3_##k;
    K8(DCL0)
    float4 wi0, wi1, wi2, wi3;
    {
      const float* b0 = Whh0 + (size_t)r0 * H_DIM + lane * 32;
      const float* b1 = b0 + H_DIM;
      const float* b2 = b0 + 2 * H_DIM;
      const float* b3 = b0 + 3 * H_DIM;
      #define LDW0(k) wa0_##k = ld4(b0 + 4*k); wa1_##k = ld4(b1 + 4*k); \
                      wa2_##k = ld4(b2 + 4*k); wa3_##k = ld4(b3 + 4*k);
      K8(LDW0)
      const float* bi = Wih0 + (size_t)r0 * I_DIM + lane * 4;
      wi0 = ld4(bi); wi1 = ld4(bi + I_DIM); wi2 = ld4(bi + 2 * I_DIM); wi3 = ld4(bi + 3 * I_DIM);
    }
    const float bs0 = bih0[r0] + bhh0[r0];
    const float bs1 = bih0[r0 + 1] + bhh0[r0 + 1];
    const float bs2 = bih0[r0 + 2] + bhh0[r0 + 2];
    const float bs3 = bih0[r0 + 3] + bhh0[r0 + 3];

    if (tid < 256) {   // re-init 8 slots of owned rows: slot0 = tagged h0_0
      int sl = tid >> 5; int r = wg * 32 + (tid & 31);
      cstore1(&h0s[sl * H_DIM + r], (sl == 0) ? 4.f : 0.f);
    }
    start_barrier(bslots, wg, tid, runbase + 1);

    for (int s = 1; s <= L_SEQ; ++s) {
      const int P = s & 1;
      if ((s & 3) == 0 && s > 4 && tid < NWG1) {   // throttle: all L1 >= s-4
        const float c = tagc(s - 4);
        const float* tp = h1s + ((s - 4) & 7) * H_DIM + tid * 16;
        while (__builtin_fabsf(cload1(tp) - c) > 1.f) {}
      }
      if (tid >= 128 && tid < 192) {               // stage x_t (pad-swizzled)
        int j = tid - 128;
        xl[P][j + (j >> 3)] = ((const float4*)x)[(size_t)(s - 1) * 64 + j];
      }
      float4 hv = poll4(h0s + ((s - 1) & 7) * H_DIM + (tid << 2), tagc(s - 1));
      h0l[P][tid + (tid >> 3)] = hv;
      __syncthreads();

      float4 p0 = {0,0,0,0}, p1 = {0,0,0,0}, p2 = {0,0,0,0}, p3 = {0,0,0,0};
      #define F0(k) { float4 h = h0l[P][9*lane + k]; \
                      MAC4(p0, wa0_##k, h) MAC4(p1, wa1_##k, h) \
                      MAC4(p2, wa2_##k, h) MAC4(p3, wa3_##k, h) }
      K8(F0)
      { float4 hx = xl[P][lane + (lane >> 3)];
        MAC4(p0, wi0, hx) MAC4(p1, wi1, hx) MAC4(p2, wi2, hx) MAC4(p3, wi3, hx) }
      float s0 = (p0.x + p0.y) + (p0.z + p0.w);
      float s1 = (p1.x + p1.y) + (p1.z + p1.w);
      float s2 = (p2.x + p2.y) + (p2.z + p2.w);
      float s3 = (p3.x + p3.y) + (p3.z + p3.w);
      #pragma unroll
      for (int m = 1; m < 64; m <<= 1) {
        s0 += __shfl_xor(s0, m); s1 += __shfl_xor(s1, m);
        s2 += __shfl_xor(s2, m); s3 += __shfl_xor(s3, m);
      }
      if (lane == 0) {
        const float ct = tagc(s);
        float* dst = h0s + (s & 7) * H_DIM + r0;
        cstore1(dst + 0, tanh_fast(s0 + bs0) + ct);
        cstore1(dst + 1, tanh_fast(s1 + bs1) + ct);
        cstore1(dst + 2, tanh_fast(s2 + bs2) + ct);
        cstore1(dst + 3, tanh_fast(s3 + bs3) + ct);
      }
    }

    if (wg == 0) {
      // FC: sigmoid(h1_8192 . Wfc + bfc); slot 0, ctr 4 (see safety proof above)
      float4 hv = poll4(h1s + (tid << 2), tagc(L_SEQ));
      float4 wf = ((const float4*)Wfc)[tid];
      float pz = hv.x * wf.x + hv.y * wf.y + hv.z * wf.z + hv.w * wf.w;
      #pragma unroll
      for (int m = 1; m < 64; m <<= 1) pz += __shfl_xor(pz, m);
      __syncthreads();
      float* red = (float*)&h0l[0][0];
      if (lane == 0) red[wv] = pz;
      __syncthreads();
      if (tid == 0) {
        float z = bfc[0];
        #pragma unroll
        for (int w = 0; w < 8; ++w) z += red[w];
        out[0] = 1.f / (1.f + __expf(-z));
        cstoreu(runctr, runbase + 1);
      }
    }
  } else {
    // ========== layer 1: rows r0, r0+1 = (wg-NWG0)*16 + wv*2 ; cols [32*lane,+32) ==========
    const int wgl = wg - NWG0;
    const int r0  = wgl * 16 + wv * 2;
    #define DCL1(k) float4 ia_##k, ib_##k, ha_##k, hb_##k;
    K8(DCL1)
    {
      const float* i0 = Wih1 + (size_t)r0 * H_DIM + lane * 32;
      const float* i1 = i0 + H_DIM;
      const float* h0b = Whh1 + (size_t)r0 * H_DIM + lane * 32;
      const float* h1b = h0b + H_DIM;
      #define LDW1(k) ia_##k = ld4(i0 + 4*k); ib_##k = ld4(i1 + 4*k); \
                      ha_##k = ld4(h0b + 4*k); hb_##k = ld4(h1b + 4*k);
      K8(LDW1)
    }
    const float ba = bih1[r0] + bhh1[r0];
    const float bb = bih1[r0 + 1] + bhh1[r0 + 1];

    if (tid < 128) {   // re-init 8 slots of owned rows: slot0 = tagged h1_0
      int sl = tid >> 4; int r = wgl * 16 + (tid & 15);
      cstore1(&h1s[sl * H_DIM + r], (sl == 0) ? 4.f : 0.f);
    }
    start_barrier(bslots, wg, tid, runbase + 1);

    for (int t = 1; t <= L_SEQ; ++t) {
      const int P = t & 1;
      float4 a, b;
      poll4x2(h0s + (t & 7) * H_DIM + (tid << 2), tagc(t),
              h1s + ((t - 1) & 7) * H_DIM + (tid << 2), tagc(t - 1), a, b);
      h0l[P][tid + (tid >> 3)] = a;
      h1l[P][tid + (tid >> 3)] = b;
      __syncthreads();

      float4 pa = {0,0,0,0}, pb = {0,0,0,0};
      #define F1(k) { float4 h = h0l[P][9*lane + k]; MAC4(pa, ia_##k, h) MAC4(pb, ib_##k, h) \
                      float4 g = h1l[P][9*lane + k]; MAC4(pa, ha_##k, g) MAC4(pb, hb_##k, g) }
      K8(F1)
      float sa = (pa.x + pa.y) + (pa.z + pa.w);
      float sb = (pb.x + pb.y) + (pb.z + pb.w);
      #pragma unroll
      for (int m = 1; m < 64; m <<= 1) {
        sa += __shfl_xor(sa, m); sb += __shfl_xor(sb, m);
      }
      if (lane == 0) {
        const float ct = tagc(t);
        float* dst = h1s + (t & 7) * H_DIM + r0;
        cstore1(dst + 0, tanh_fast(sa + ba) + ct);
        cstore1(dst + 1, tanh_fast(sb + bb) + ct);
      }
    }
  }
}

extern "C" void kernel_launch(void* const* d_in, const int* in_sizes, int n_in,
                              void* d_out, int out_size, void* d_ws, size_t ws_size,
                              hipStream_t stream) {
  const float* xx   = (const float*)d_in[0];
  const float* Wih0 = (const float*)d_in[1];
  const float* Whh0 = (const float*)d_in[2];
  const float* bih0 = (const float*)d_in[3];
  const float* bhh0 = (const float*)d_in[4];
  const float* Wih1 = (const float*)d_in[5];
  const float* Whh1 = (const float*)d_in[6];
  const float* bih1 = (const float*)d_in[7];
  const float* bhh1 = (const float*)d_in[8];
  const float* Wfc  = (const float*)d_in[9];
  const float* bfc  = (const float*)d_in[10];

  unsigned* runctr = (unsigned*)d_ws;
  unsigned* bslots = (unsigned*)((char*)d_ws + 256);
  float* h0s       = (float*)((char*)d_ws + 4096);
  float* h1s       = (float*)((char*)d_ws + 4096 + 8 * H_DIM * sizeof(float));

  rnn2_colblock<<<dim3(NWG), dim3(TPB), 0, stream>>>(
      xx, Wih0, Whh0, bih0, bhh0, Wih1, Whh1, bih1, bhh1, Wfc, bfc,
      (float*)d_out, runctr, bslots, h0s, h1s);
}